// Round 1
// baseline (28446.268 us; speedup 1.0000x reference)
//
#include <hip/hip_runtime.h>
#include <math.h>

// ---------------- problem constants ----------------
constexpr int L_ = 4, E_ = 512, Hn_ = 8, X_ = 8, Kk_ = 2, V_ = 32000;
constexpr int B_ = 8, T_ = 1024, HIGH_ = 32000, HID_ = 1024;
constexpr int Dh_ = E_ / Hn_;      // 64
constexpr int HALF_ = Dh_ / 2;     // 32
constexpr int NTOK = B_ * T_;      // 8192
constexpr int CAP_ = NTOK * Kk_ / X_; // 2048
constexpr int FF_ = 4 * E_;        // 2048

__device__ __forceinline__ float wave_sum(float v) {
#pragma unroll
  for (int off = 32; off; off >>= 1) v += __shfl_xor(v, off, 64);
  return v;
}
__device__ __forceinline__ float wave_max(float v) {
#pragma unroll
  for (int off = 32; off; off >>= 1) v = fmaxf(v, __shfl_xor(v, off, 64));
  return v;
}

// ---------------- embedding ----------------
__global__ __launch_bounds__(256)
void embed_kernel(const float* __restrict__ tok_emb, const float* __restrict__ pos_emb,
                  const int* __restrict__ ids, float* __restrict__ x) {
  int tok = blockIdx.x;
  int t = tok & (T_ - 1);
  int id = ids[tok];
  const float* te = tok_emb + (size_t)id * E_;
  const float* pe = pos_emb + (size_t)t * E_;
  float* xr = x + (size_t)tok * E_;
  int tid = threadIdx.x;
  xr[tid]       = te[tid]       + pe[tid];
  xr[tid + 256] = te[tid + 256] + pe[tid + 256];
}

// ---------------- layernorm (one block per token, E=512) ----------------
__global__ __launch_bounds__(256)
void ln_kernel(const float* __restrict__ x, const float* __restrict__ w,
               const float* __restrict__ b, float* __restrict__ o) {
  int row = blockIdx.x, tid = threadIdx.x;
  const float* xr = x + (size_t)row * E_;
  float a0 = xr[tid], a1 = xr[tid + 256];
  __shared__ float red[4];
  float s = wave_sum(a0 + a1);
  if ((tid & 63) == 0) red[tid >> 6] = s;
  __syncthreads();
  float mean = (red[0] + red[1] + red[2] + red[3]) * (1.f / E_);
  float d0 = a0 - mean, d1 = a1 - mean;
  __syncthreads();
  float sq = wave_sum(d0 * d0 + d1 * d1);
  if ((tid & 63) == 0) red[tid >> 6] = sq;
  __syncthreads();
  float var = (red[0] + red[1] + red[2] + red[3]) * (1.f / E_);
  float rstd = 1.f / sqrtf(var + 1e-5f);
  float* orow = o + (size_t)row * E_;
  orow[tid]       = d0 * rstd * w[tid]       + b[tid];
  orow[tid + 256] = d1 * rstd * w[tid + 256] + b[tid + 256];
}

// ---------------- generic tiled GEMM: C = [C +] A @ W^T [+ bias] [relu] ----------------
// A: (M,K) row-major with row pitch lda. W: (N,K) row-major. C: (M,N).
constexpr int BM = 64, BN = 64, BK = 16;

__global__ __launch_bounds__(256)
void gemm_kernel(const float* __restrict__ A, int lda,
                 const float* __restrict__ W, const float* __restrict__ bias,
                 float* __restrict__ C, int M, int N, int K, int relu, int accum) {
  __shared__ float As[BK][BM + 1];
  __shared__ float Bs[BK][BN + 1];
  int n0 = blockIdx.x * BN, m0 = blockIdx.y * BM;
  int tid = threadIdx.x;
  int tm = tid >> 4, tn = tid & 15;
  int ldr = tid >> 2, ldc = (tid & 3) << 2;
  float acc[4][4] = {};
  for (int k0 = 0; k0 < K; k0 += BK) {
    float4 av = make_float4(0.f, 0.f, 0.f, 0.f), wv = make_float4(0.f, 0.f, 0.f, 0.f);
    int m = m0 + ldr;
    if (m < M) av = *(const float4*)(A + (size_t)m * lda + k0 + ldc);
    int n = n0 + ldr;
    if (n < N) wv = *(const float4*)(W + (size_t)n * K + k0 + ldc);
    As[ldc + 0][ldr] = av.x; As[ldc + 1][ldr] = av.y; As[ldc + 2][ldr] = av.z; As[ldc + 3][ldr] = av.w;
    Bs[ldc + 0][ldr] = wv.x; Bs[ldc + 1][ldr] = wv.y; Bs[ldc + 2][ldr] = wv.z; Bs[ldc + 3][ldr] = wv.w;
    __syncthreads();
#pragma unroll
    for (int k = 0; k < BK; ++k) {
      float a[4], bb[4];
#pragma unroll
      for (int i = 0; i < 4; ++i) a[i] = As[k][tm * 4 + i];
#pragma unroll
      for (int j = 0; j < 4; ++j) bb[j] = Bs[k][tn * 4 + j];
#pragma unroll
      for (int i = 0; i < 4; ++i)
#pragma unroll
        for (int j = 0; j < 4; ++j) acc[i][j] += a[i] * bb[j];
    }
    __syncthreads();
  }
#pragma unroll
  for (int i = 0; i < 4; ++i) {
    int m = m0 + tm * 4 + i;
    if (m >= M) continue;
#pragma unroll
    for (int j = 0; j < 4; ++j) {
      int n = n0 + tn * 4 + j;
      if (n >= N) continue;
      float v = acc[i][j];
      if (bias) v += bias[n];
      if (accum) v += C[(size_t)m * N + n];
      if (relu) v = fmaxf(v, 0.f);
      C[(size_t)m * N + n] = v;
    }
  }
}

// ---------------- expert up-proj: C = relu(A[rows] @ W^T + bias) ----------------
__global__ __launch_bounds__(256)
void gemm_gather_kernel(const float* __restrict__ Abase, const int* __restrict__ rows,
                        const float* __restrict__ W, const float* __restrict__ bias,
                        float* __restrict__ C, int M, int N, int K) {
  __shared__ float As[BK][BM + 1];
  __shared__ float Bs[BK][BN + 1];
  int n0 = blockIdx.x * BN, m0 = blockIdx.y * BM;
  int tid = threadIdx.x;
  int tm = tid >> 4, tn = tid & 15;
  int ldr = tid >> 2, ldc = (tid & 3) << 2;
  int arow = rows[m0 + ldr];  // M is a multiple of 64 (CAP_), no guard needed
  const float* Aptr = Abase + (size_t)arow * K;
  const float* Wptr = W + (size_t)(n0 + ldr) * K;
  float acc[4][4] = {};
  for (int k0 = 0; k0 < K; k0 += BK) {
    float4 av = *(const float4*)(Aptr + k0 + ldc);
    float4 wv = *(const float4*)(Wptr + k0 + ldc);
    As[ldc + 0][ldr] = av.x; As[ldc + 1][ldr] = av.y; As[ldc + 2][ldr] = av.z; As[ldc + 3][ldr] = av.w;
    Bs[ldc + 0][ldr] = wv.x; Bs[ldc + 1][ldr] = wv.y; Bs[ldc + 2][ldr] = wv.z; Bs[ldc + 3][ldr] = wv.w;
    __syncthreads();
#pragma unroll
    for (int k = 0; k < BK; ++k) {
      float a[4], bb[4];
#pragma unroll
      for (int i = 0; i < 4; ++i) a[i] = As[k][tm * 4 + i];
#pragma unroll
      for (int j = 0; j < 4; ++j) bb[j] = Bs[k][tn * 4 + j];
#pragma unroll
      for (int i = 0; i < 4; ++i)
#pragma unroll
        for (int j = 0; j < 4; ++j) acc[i][j] += a[i] * bb[j];
    }
    __syncthreads();
  }
#pragma unroll
  for (int i = 0; i < 4; ++i) {
    int m = m0 + tm * 4 + i;
#pragma unroll
    for (int j = 0; j < 4; ++j) {
      int n = n0 + tn * 4 + j;
      C[(size_t)m * N + n] = fmaxf(acc[i][j] + bias[n], 0.f);
    }
  }
}

// ---------------- expert down-proj + gated scatter: X[rows[m]] += (A@W^T + b)*g ----------------
__global__ __launch_bounds__(256)
void gemm_scatter_kernel(const float* __restrict__ A, const float* __restrict__ W,
                         const float* __restrict__ bias, const int* __restrict__ rows,
                         const float* __restrict__ gates, float* __restrict__ Xo,
                         int M, int N, int K) {
  __shared__ float As[BK][BM + 1];
  __shared__ float Bs[BK][BN + 1];
  int n0 = blockIdx.x * BN, m0 = blockIdx.y * BM;
  int tid = threadIdx.x;
  int tm = tid >> 4, tn = tid & 15;
  int ldr = tid >> 2, ldc = (tid & 3) << 2;
  const float* Aptr = A + (size_t)(m0 + ldr) * K;
  const float* Wptr = W + (size_t)(n0 + ldr) * K;
  float acc[4][4] = {};
  for (int k0 = 0; k0 < K; k0 += BK) {
    float4 av = *(const float4*)(Aptr + k0 + ldc);
    float4 wv = *(const float4*)(Wptr + k0 + ldc);
    As[ldc + 0][ldr] = av.x; As[ldc + 1][ldr] = av.y; As[ldc + 2][ldr] = av.z; As[ldc + 3][ldr] = av.w;
    Bs[ldc + 0][ldr] = wv.x; Bs[ldc + 1][ldr] = wv.y; Bs[ldc + 2][ldr] = wv.z; Bs[ldc + 3][ldr] = wv.w;
    __syncthreads();
#pragma unroll
    for (int k = 0; k < BK; ++k) {
      float a[4], bb[4];
#pragma unroll
      for (int i = 0; i < 4; ++i) a[i] = As[k][tm * 4 + i];
#pragma unroll
      for (int j = 0; j < 4; ++j) bb[j] = Bs[k][tn * 4 + j];
#pragma unroll
      for (int i = 0; i < 4; ++i)
#pragma unroll
        for (int j = 0; j < 4; ++j) acc[i][j] += a[i] * bb[j];
    }
    __syncthreads();
  }
#pragma unroll
  for (int i = 0; i < 4; ++i) {
    int m = m0 + tm * 4 + i;
    int tokr = rows[m];
    float g = gates[m];
    if (g != 0.f) {  // pad slots add exactly 0 in ref; skipping avoids RMW races on token 0
#pragma unroll
      for (int j = 0; j < 4; ++j) {
        int n = n0 + tn * 4 + j;
        Xo[(size_t)tokr * N + n] += (acc[i][j] + bias[n]) * g;
      }
    }
  }
}

// ---------------- RoPE in-place on q,k inside qkv ----------------
__global__ __launch_bounds__(256)
void rope_kernel(float* __restrict__ qkv) {
  int tok = blockIdx.x;
  int t = tok & (T_ - 1);
  int hh = threadIdx.x >> 5, j = threadIdx.x & 31;
  float inv = __expf((float)j * (-logf(10000.f) / 32.f));  // 10000^(-j/32)
  float ang = (float)t * inv;
  float sn = sinf(ang), cs = cosf(ang);
  float* qp = qkv + (size_t)tok * 3 * E_ + hh * Dh_;
  float* kp = qp + E_;
  float q1 = qp[j], q2 = qp[j + HALF_];
  qp[j] = q1 * cs - q2 * sn;
  qp[j + HALF_] = q2 * cs + q1 * sn;
  float k1 = kp[j], k2 = kp[j + HALF_];
  kp[j] = k1 * cs - k2 * sn;
  kp[j + HALF_] = k2 * cs + k1 * sn;
}

// ---------------- attention: one wave per (b,h,t) query row, online softmax ----------------
// Output written in the reference's SCRAMBLED reshape layout:
//   (b,h,t,d) -> row = b*T + h*128 + t/8, col = (t%8)*64 + d
__global__ __launch_bounds__(64)
void attn_kernel(const float* __restrict__ qkv, float* __restrict__ att) {
  int idx = blockIdx.x;
  int t = idx & (T_ - 1);
  int bh = idx >> 10;
  int hh = bh & (Hn_ - 1);
  int b = bh >> 3;
  int lane = threadIdx.x;
  const float* base = qkv + (size_t)b * T_ * 3 * E_;
  float qd = base[(size_t)t * 3 * E_ + hh * Dh_ + lane];
  float m = -1e30f, l = 0.f, acc = 0.f;
  for (int s = 0; s < T_; ++s) {
    const float* kp = base + (size_t)s * 3 * E_ + E_ + hh * Dh_;
    const float* vp = kp + E_;
    float d = wave_sum(qd * kp[lane]) * 0.125f;  // 1/sqrt(64)
    float nm = fmaxf(m, d);
    float alpha = __expf(m - nm);
    float p = __expf(d - nm);
    l = l * alpha + p;
    acc = acc * alpha + p * vp[lane];
    m = nm;
  }
  size_t row = (size_t)b * T_ + hh * 128 + (t >> 3);
  att[row * E_ + ((t & 7) * Dh_) + lane] = acc / l;
}

// ---------------- router: logits, noisy top-2, gates ----------------
__global__ __launch_bounds__(64)
void router_kernel(const float* __restrict__ h,
                   const float* __restrict__ rw, const float* __restrict__ rb,
                   const float* __restrict__ nw, const float* __restrict__ nb,
                   const float* __restrict__ noise,
                   int* __restrict__ topi, float* __restrict__ topg) {
  int tok = blockIdx.x;
  int lane = threadIdx.x;
  const float* hr = h + (size_t)tok * E_;
  __shared__ float lg[X_], nl[X_];
  for (int xj = 0; xj < X_; ++xj) {
    float a = 0.f, c = 0.f;
    for (int dd = lane; dd < E_; dd += 64) {
      float hv = hr[dd];
      a += hv * rw[xj * E_ + dd];
      c += hv * nw[xj * E_ + dd];
    }
    a = wave_sum(a);
    c = wave_sum(c);
    if (lane == 0) { lg[xj] = a + rb[xj]; nl[xj] = c + nb[xj]; }
  }
  __syncthreads();
  if (lane == 0) {
    float noisy[X_];
#pragma unroll
    for (int xj = 0; xj < X_; ++xj) {
      float nv = nl[xj];
      float sp = fmaxf(nv, 0.f) + log1pf(expf(-fabsf(nv)));  // stable softplus
      noisy[xj] = lg[xj] + noise[(size_t)tok * X_ + xj] * sp;
    }
    int i0 = 0;
#pragma unroll
    for (int xj = 1; xj < X_; ++xj) if (noisy[xj] > noisy[i0]) i0 = xj;  // ties -> lower index
    int i1 = -1;
#pragma unroll
    for (int xj = 0; xj < X_; ++xj) {
      if (xj == i0) continue;
      if (i1 < 0 || noisy[xj] > noisy[i1]) i1 = xj;
    }
    float e = __expf(noisy[i1] - noisy[i0]);
    float p0 = 1.f / (1.f + e);
    topi[tok * 2] = i0;
    topi[tok * 2 + 1] = i1;
    topg[tok * 2] = p0;
    topg[tok * 2 + 1] = e * p0;
  }
}

// ---------------- per-expert ordered compaction with capacity ----------------
__global__ __launch_bounds__(256)
void build_lists_kernel(const int* __restrict__ topi, const float* __restrict__ topg,
                        int* __restrict__ elist, float* __restrict__ eg) {
  int ex = blockIdx.x;
  int tid = threadIdx.x;
  constexpr int PER = NTOK / 256;  // 32 tokens per thread, contiguous => order preserved
  int base = tid * PER;
  int cnt = 0;
  for (int i = 0; i < PER; ++i) {
    int t = base + i;
    if (topi[2 * t] == ex || topi[2 * t + 1] == ex) cnt++;
  }
  __shared__ int s[256];
  s[tid] = cnt;
  __syncthreads();
  for (int off = 1; off < 256; off <<= 1) {  // Hillis-Steele inclusive scan
    int v = (tid >= off) ? s[tid - off] : 0;
    __syncthreads();
    s[tid] += v;
    __syncthreads();
  }
  int rank = s[tid] - cnt;  // exclusive prefix
  int total = s[255];
  for (int i = 0; i < PER; ++i) {
    int t = base + i;
    int k0 = topi[2 * t], k1 = topi[2 * t + 1];
    if (k0 == ex || k1 == ex) {
      if (rank < CAP_) {
        elist[ex * CAP_ + rank] = t;
        eg[ex * CAP_ + rank] = (k0 == ex) ? topg[2 * t] : topg[2 * t + 1];
      }
      rank++;  // overflow beyond CAP_ dropped, like jnp.nonzero(size=cap)
    }
  }
  for (int i = total + tid; i < CAP_; i += 256) {  // padding: token 0, gate 0
    elist[ex * CAP_ + i] = 0;
    eg[ex * CAP_ + i] = 0.f;
  }
}

// ---------------- pooling + head ----------------
__global__ __launch_bounds__(64)
void pool_score_kernel(const float* __restrict__ h, const float* __restrict__ q,
                       float* __restrict__ s) {
  int tok = blockIdx.x;
  int lane = threadIdx.x;
  const float* hr = h + (size_t)tok * E_;
  float a = 0.f;
  for (int dd = lane; dd < E_; dd += 64) a += hr[dd] * q[dd];
  a = wave_sum(a);
  if (lane == 0) s[tok] = a * (1.f / sqrtf((float)E_));
}

__global__ __launch_bounds__(256)
void pool_softmax_kernel(const float* __restrict__ s, float* __restrict__ w) {
  int b = blockIdx.x, tid = threadIdx.x;
  const float* sr = s + (size_t)b * T_;
  float v[4];
  float mx = -1e30f;
#pragma unroll
  for (int i = 0; i < 4; ++i) { v[i] = sr[tid + 256 * i]; mx = fmaxf(mx, v[i]); }
  __shared__ float red[4];
  mx = wave_max(mx);
  if ((tid & 63) == 0) red[tid >> 6] = mx;
  __syncthreads();
  mx = fmaxf(fmaxf(red[0], red[1]), fmaxf(red[2], red[3]));
  float e[4], sum = 0.f;
#pragma unroll
  for (int i = 0; i < 4; ++i) { e[i] = __expf(v[i] - mx); sum += e[i]; }
  sum = wave_sum(sum);
  __syncthreads();
  if ((tid & 63) == 0) red[tid >> 6] = sum;
  __syncthreads();
  float inv = 1.f / (red[0] + red[1] + red[2] + red[3]);
#pragma unroll
  for (int i = 0; i < 4; ++i) w[(size_t)b * T_ + tid + 256 * i] = e[i] * inv;
}

__global__ __launch_bounds__(512)
void pool_weighted_kernel(const float* __restrict__ w, const float* __restrict__ h,
                          float* __restrict__ pooled) {
  int b = blockIdx.x, e = threadIdx.x;
  float acc = 0.f;
  for (int t = 0; t < T_; ++t) acc += w[(size_t)b * T_ + t] * h[((size_t)b * T_ + t) * E_ + e];
  pooled[(size_t)b * E_ + e] = acc;
}

__global__ __launch_bounds__(256)
void head2_kernel(const float* __restrict__ h1, const float* __restrict__ w2,
                  const float* __restrict__ b2, float* __restrict__ out) {
  int b = blockIdx.x, tid = threadIdx.x;
  float a = 0.f;
  for (int j = tid; j < HID_; j += 256) a += h1[(size_t)b * HID_ + j] * w2[j];
  a = wave_sum(a);
  __shared__ float red[4];
  if ((tid & 63) == 0) red[tid >> 6] = a;
  __syncthreads();
  if (tid == 0) out[b] = red[0] + red[1] + red[2] + red[3] + b2[0];
}

// ---------------- host launcher ----------------
extern "C" void kernel_launch(void* const* d_in, const int* in_sizes, int n_in,
                              void* d_out, int out_size, void* d_ws, size_t ws_size,
                              hipStream_t stream) {
  const float* tok_emb = (const float*)d_in[0];
  const float* pos_emb = (const float*)d_in[1];
  const float* ln1_w = (const float*)d_in[2];
  const float* ln1_b = (const float*)d_in[3];
  const float* ln2_w = (const float*)d_in[4];
  const float* ln2_b = (const float*)d_in[5];
  const float* qkv_w = (const float*)d_in[6];
  const float* out_w = (const float*)d_in[7];
  const float* route_w = (const float*)d_in[8];
  const float* route_b = (const float*)d_in[9];
  const float* noise_w = (const float*)d_in[10];
  const float* noise_b = (const float*)d_in[11];
  const float* exp_w1 = (const float*)d_in[12];
  const float* exp_b1 = (const float*)d_in[13];
  const float* exp_w2 = (const float*)d_in[14];
  const float* exp_b2 = (const float*)d_in[15];
  const float* lnf_w = (const float*)d_in[16];
  const float* lnf_b = (const float*)d_in[17];
  const float* pool_q = (const float*)d_in[18];
  const float* pool_w = (const float*)d_in[19];
  const float* pool_b = (const float*)d_in[20];
  const float* head_w1 = (const float*)d_in[21];
  const float* head_b1 = (const float*)d_in[22];
  const float* head_w2 = (const float*)d_in[23];
  const float* head_b2 = (const float*)d_in[24];
  const int* ids = (const int*)d_in[25];
  const float* rnoise = (const float*)d_in[26];
  float* out = (float*)d_out;
  (void)in_sizes; (void)n_in; (void)out_size; (void)ws_size;

  // workspace layout (fp32 units); total ~113 MB
  float* ws = (float*)d_ws;
  float* x = ws;        ws += (size_t)NTOK * E_;
  float* h = ws;        ws += (size_t)NTOK * E_;
  float* qkv = ws;      ws += (size_t)NTOK * 3 * E_;
  float* att = ws;      ws += (size_t)NTOK * E_;
  float* hid = ws;      ws += (size_t)CAP_ * FF_;
  float* sbuf = ws;     ws += NTOK;
  float* wbuf = ws;     ws += NTOK;
  float* pooled = ws;   ws += B_ * E_;
  float* hv = ws;       ws += B_ * HIGH_;
  float* h1 = ws;       ws += B_ * HID_;
  float* topg = ws;     ws += NTOK * 2;
  float* eg = ws;       ws += X_ * CAP_;
  int* topi = (int*)ws; ws += NTOK * 2;
  int* elist = (int*)ws;

  embed_kernel<<<NTOK, 256, 0, stream>>>(tok_emb, pos_emb, ids, x);

  for (int l = 0; l < L_; ++l) {
    ln_kernel<<<NTOK, 256, 0, stream>>>(x, ln1_w + l * E_, ln1_b + l * E_, h);
    {
      dim3 g(3 * E_ / BN, NTOK / BM);
      gemm_kernel<<<g, 256, 0, stream>>>(h, E_, qkv_w + (size_t)l * 3 * E_ * E_, nullptr,
                                         qkv, NTOK, 3 * E_, E_, 0, 0);
    }
    rope_kernel<<<NTOK, 256, 0, stream>>>(qkv);
    attn_kernel<<<B_ * Hn_ * T_, 64, 0, stream>>>(qkv, att);
    {
      dim3 g(E_ / BN, NTOK / BM);  // x += att @ out_w^T
      gemm_kernel<<<g, 256, 0, stream>>>(att, E_, out_w + (size_t)l * E_ * E_, nullptr,
                                         x, NTOK, E_, E_, 0, 1);
    }
    ln_kernel<<<NTOK, 256, 0, stream>>>(x, ln2_w + l * E_, ln2_b + l * E_, h);
    router_kernel<<<NTOK, 64, 0, stream>>>(h, route_w + (size_t)l * X_ * E_, route_b + l * X_,
                                           noise_w + (size_t)l * X_ * E_, noise_b + l * X_,
                                           rnoise + (size_t)l * NTOK * X_, topi, topg);
    build_lists_kernel<<<X_, 256, 0, stream>>>(topi, topg, elist, eg);
    for (int ex = 0; ex < X_; ++ex) {
      const float* w1 = exp_w1 + (size_t)(l * X_ + ex) * FF_ * E_;
      const float* b1 = exp_b1 + (size_t)(l * X_ + ex) * FF_;
      const float* w2 = exp_w2 + (size_t)(l * X_ + ex) * E_ * FF_;
      const float* b2 = exp_b2 + (size_t)(l * X_ + ex) * E_;
      {
        dim3 g(FF_ / BN, CAP_ / BM);
        gemm_gather_kernel<<<g, 256, 0, stream>>>(h, elist + ex * CAP_, w1, b1, hid,
                                                  CAP_, FF_, E_);
      }
      {
        dim3 g(E_ / BN, CAP_ / BM);
        gemm_scatter_kernel<<<g, 256, 0, stream>>>(hid, w2, b2, elist + ex * CAP_,
                                                   eg + ex * CAP_, x, CAP_, E_, FF_);
      }
    }
  }

  ln_kernel<<<NTOK, 256, 0, stream>>>(x, lnf_w, lnf_b, h);
  pool_score_kernel<<<NTOK, 64, 0, stream>>>(h, pool_q, sbuf);
  pool_softmax_kernel<<<B_, 256, 0, stream>>>(sbuf, wbuf);
  pool_weighted_kernel<<<B_, 512, 0, stream>>>(wbuf, h, pooled);
  {
    dim3 g(HIGH_ / BN, 1);
    gemm_kernel<<<g, 256, 0, stream>>>(pooled, E_, pool_w, pool_b, hv, B_, HIGH_, E_, 0, 0);
  }
  {
    dim3 g(HID_ / BN, 1);
    gemm_kernel<<<g, 256, 0, stream>>>(hv, HIGH_, head_w1, head_b1, h1, B_, HID_, HIGH_, 1, 0);
  }
  head2_kernel<<<B_, 256, 0, stream>>>(h1, head_w2, head_b2, out);
}

// Round 2
// 17414.445 us; speedup vs baseline: 1.6335x; 1.6335x over previous
//
#include <hip/hip_runtime.h>
#include <math.h>

// ---------------- problem constants ----------------
constexpr int L_ = 4, E_ = 512, Hn_ = 8, X_ = 8, Kk_ = 2, V_ = 32000;
constexpr int B_ = 8, T_ = 1024, HIGH_ = 32000, HID_ = 1024;
constexpr int Dh_ = E_ / Hn_;      // 64
constexpr int HALF_ = Dh_ / 2;     // 32
constexpr int NTOK = B_ * T_;      // 8192
constexpr int CAP_ = NTOK * Kk_ / X_; // 2048
constexpr int FF_ = 4 * E_;        // 2048

__device__ __forceinline__ float wave_sum(float v) {
#pragma unroll
  for (int off = 32; off; off >>= 1) v += __shfl_xor(v, off, 64);
  return v;
}
__device__ __forceinline__ float wave_max(float v) {
#pragma unroll
  for (int off = 32; off; off >>= 1) v = fmaxf(v, __shfl_xor(v, off, 64));
  return v;
}

// ---------------- embedding ----------------
__global__ __launch_bounds__(256)
void embed_kernel(const float* __restrict__ tok_emb, const float* __restrict__ pos_emb,
                  const int* __restrict__ ids, float* __restrict__ x) {
  int tok = blockIdx.x;
  int t = tok & (T_ - 1);
  int id = ids[tok];
  const float* te = tok_emb + (size_t)id * E_;
  const float* pe = pos_emb + (size_t)t * E_;
  float* xr = x + (size_t)tok * E_;
  int tid = threadIdx.x;
  xr[tid]       = te[tid]       + pe[tid];
  xr[tid + 256] = te[tid + 256] + pe[tid + 256];
}

// ---------------- layernorm (one block per token, E=512) ----------------
__global__ __launch_bounds__(256)
void ln_kernel(const float* __restrict__ x, const float* __restrict__ w,
               const float* __restrict__ b, float* __restrict__ o) {
  int row = blockIdx.x, tid = threadIdx.x;
  const float* xr = x + (size_t)row * E_;
  float a0 = xr[tid], a1 = xr[tid + 256];
  __shared__ float red[4];
  float s = wave_sum(a0 + a1);
  if ((tid & 63) == 0) red[tid >> 6] = s;
  __syncthreads();
  float mean = (red[0] + red[1] + red[2] + red[3]) * (1.f / E_);
  float d0 = a0 - mean, d1 = a1 - mean;
  __syncthreads();
  float sq = wave_sum(d0 * d0 + d1 * d1);
  if ((tid & 63) == 0) red[tid >> 6] = sq;
  __syncthreads();
  float var = (red[0] + red[1] + red[2] + red[3]) * (1.f / E_);
  float rstd = 1.f / sqrtf(var + 1e-5f);
  float* orow = o + (size_t)row * E_;
  orow[tid]       = d0 * rstd * w[tid]       + b[tid];
  orow[tid + 256] = d1 * rstd * w[tid + 256] + b[tid + 256];
}

// ---------------- generic tiled GEMM: C = [C +] A @ W^T [+ bias] [relu] ----------------
constexpr int BM = 64, BN = 64, BK = 16;

__global__ __launch_bounds__(256)
void gemm_kernel(const float* __restrict__ A, int lda,
                 const float* __restrict__ W, const float* __restrict__ bias,
                 float* __restrict__ C, int M, int N, int K, int relu, int accum) {
  __shared__ float As[BK][BM + 1];
  __shared__ float Bs[BK][BN + 1];
  int n0 = blockIdx.x * BN, m0 = blockIdx.y * BM;
  int tid = threadIdx.x;
  int tm = tid >> 4, tn = tid & 15;
  int ldr = tid >> 2, ldc = (tid & 3) << 2;
  float acc[4][4] = {};
  for (int k0 = 0; k0 < K; k0 += BK) {
    float4 av = make_float4(0.f, 0.f, 0.f, 0.f), wv = make_float4(0.f, 0.f, 0.f, 0.f);
    int m = m0 + ldr;
    if (m < M) av = *(const float4*)(A + (size_t)m * lda + k0 + ldc);
    int n = n0 + ldr;
    if (n < N) wv = *(const float4*)(W + (size_t)n * K + k0 + ldc);
    As[ldc + 0][ldr] = av.x; As[ldc + 1][ldr] = av.y; As[ldc + 2][ldr] = av.z; As[ldc + 3][ldr] = av.w;
    Bs[ldc + 0][ldr] = wv.x; Bs[ldc + 1][ldr] = wv.y; Bs[ldc + 2][ldr] = wv.z; Bs[ldc + 3][ldr] = wv.w;
    __syncthreads();
#pragma unroll
    for (int k = 0; k < BK; ++k) {
      float a[4], bb[4];
#pragma unroll
      for (int i = 0; i < 4; ++i) a[i] = As[k][tm * 4 + i];
#pragma unroll
      for (int j = 0; j < 4; ++j) bb[j] = Bs[k][tn * 4 + j];
#pragma unroll
      for (int i = 0; i < 4; ++i)
#pragma unroll
        for (int j = 0; j < 4; ++j) acc[i][j] += a[i] * bb[j];
    }
    __syncthreads();
  }
#pragma unroll
  for (int i = 0; i < 4; ++i) {
    int m = m0 + tm * 4 + i;
    if (m >= M) continue;
#pragma unroll
    for (int j = 0; j < 4; ++j) {
      int n = n0 + tn * 4 + j;
      if (n >= N) continue;
      float v = acc[i][j];
      if (bias) v += bias[n];
      if (accum) v += C[(size_t)m * N + n];
      if (relu) v = fmaxf(v, 0.f);
      C[(size_t)m * N + n] = v;
    }
  }
}

// ---------------- batched expert up-proj: hid[z] = relu(h[rows_z] @ W1_z^T + b1_z) ----------------
__global__ __launch_bounds__(256)
void gemm_gather_kernel(const float* __restrict__ Abase, const int* __restrict__ elist,
                        const float* __restrict__ W1, const float* __restrict__ b1,
                        float* __restrict__ hid, int e0) {
  int ez = blockIdx.z;
  int ex = e0 + ez;
  const int* rows = elist + ex * CAP_;
  const float* W = W1 + (size_t)ex * FF_ * E_;
  const float* bias = b1 + (size_t)ex * FF_;
  float* C = hid + (size_t)ez * CAP_ * FF_;
  constexpr int N = FF_, K = E_;

  __shared__ float As[BK][BM + 1];
  __shared__ float Bs[BK][BN + 1];
  int n0 = blockIdx.x * BN, m0 = blockIdx.y * BM;
  int tid = threadIdx.x;
  int tm = tid >> 4, tn = tid & 15;
  int ldr = tid >> 2, ldc = (tid & 3) << 2;
  int arow = rows[m0 + ldr];
  const float* Aptr = Abase + (size_t)arow * K;
  const float* Wptr = W + (size_t)(n0 + ldr) * K;
  float acc[4][4] = {};
  for (int k0 = 0; k0 < K; k0 += BK) {
    float4 av = *(const float4*)(Aptr + k0 + ldc);
    float4 wv = *(const float4*)(Wptr + k0 + ldc);
    As[ldc + 0][ldr] = av.x; As[ldc + 1][ldr] = av.y; As[ldc + 2][ldr] = av.z; As[ldc + 3][ldr] = av.w;
    Bs[ldc + 0][ldr] = wv.x; Bs[ldc + 1][ldr] = wv.y; Bs[ldc + 2][ldr] = wv.z; Bs[ldc + 3][ldr] = wv.w;
    __syncthreads();
#pragma unroll
    for (int k = 0; k < BK; ++k) {
      float a[4], bb[4];
#pragma unroll
      for (int i = 0; i < 4; ++i) a[i] = As[k][tm * 4 + i];
#pragma unroll
      for (int j = 0; j < 4; ++j) bb[j] = Bs[k][tn * 4 + j];
#pragma unroll
      for (int i = 0; i < 4; ++i)
#pragma unroll
        for (int j = 0; j < 4; ++j) acc[i][j] += a[i] * bb[j];
    }
    __syncthreads();
  }
#pragma unroll
  for (int i = 0; i < 4; ++i) {
    int m = m0 + tm * 4 + i;
#pragma unroll
    for (int j = 0; j < 4; ++j) {
      int n = n0 + tn * 4 + j;
      C[(size_t)m * N + n] = fmaxf(acc[i][j] + bias[n], 0.f);
    }
  }
}

// ---- batched expert down-proj + gated scatter: X[rows_z[m]] += (hid[z]@W2_z^T + b2_z)*g (atomic) ----
__global__ __launch_bounds__(256)
void gemm_scatter_kernel(const float* __restrict__ hid, const float* __restrict__ W2,
                         const float* __restrict__ b2, const int* __restrict__ elist,
                         const float* __restrict__ egates, float* __restrict__ Xo, int e0) {
  int ez = blockIdx.z;
  int ex = e0 + ez;
  const float* A = hid + (size_t)ez * CAP_ * FF_;
  const float* W = W2 + (size_t)ex * E_ * FF_;
  const float* bias = b2 + (size_t)ex * E_;
  const int* rows = elist + ex * CAP_;
  const float* gates = egates + ex * CAP_;
  constexpr int N = E_, K = FF_;

  __shared__ float As[BK][BM + 1];
  __shared__ float Bs[BK][BN + 1];
  int n0 = blockIdx.x * BN, m0 = blockIdx.y * BM;
  int tid = threadIdx.x;
  int tm = tid >> 4, tn = tid & 15;
  int ldr = tid >> 2, ldc = (tid & 3) << 2;
  const float* Aptr = A + (size_t)(m0 + ldr) * K;
  const float* Wptr = W + (size_t)(n0 + ldr) * K;
  float acc[4][4] = {};
  for (int k0 = 0; k0 < K; k0 += BK) {
    float4 av = *(const float4*)(Aptr + k0 + ldc);
    float4 wv = *(const float4*)(Wptr + k0 + ldc);
    As[ldc + 0][ldr] = av.x; As[ldc + 1][ldr] = av.y; As[ldc + 2][ldr] = av.z; As[ldc + 3][ldr] = av.w;
    Bs[ldc + 0][ldr] = wv.x; Bs[ldc + 1][ldr] = wv.y; Bs[ldc + 2][ldr] = wv.z; Bs[ldc + 3][ldr] = wv.w;
    __syncthreads();
#pragma unroll
    for (int k = 0; k < BK; ++k) {
      float a[4], bb[4];
#pragma unroll
      for (int i = 0; i < 4; ++i) a[i] = As[k][tm * 4 + i];
#pragma unroll
      for (int j = 0; j < 4; ++j) bb[j] = Bs[k][tn * 4 + j];
#pragma unroll
      for (int i = 0; i < 4; ++i)
#pragma unroll
        for (int j = 0; j < 4; ++j) acc[i][j] += a[i] * bb[j];
    }
    __syncthreads();
  }
#pragma unroll
  for (int i = 0; i < 4; ++i) {
    int m = m0 + tm * 4 + i;
    int tokr = rows[m];
    float g = gates[m];
    if (g != 0.f) {
#pragma unroll
      for (int j = 0; j < 4; ++j) {
        int n = n0 + tn * 4 + j;
        atomicAdd(&Xo[(size_t)tokr * N + n], (acc[i][j] + bias[n]) * g);
      }
    }
  }
}

// ---------------- RoPE in-place on q,k inside qkv ----------------
__global__ __launch_bounds__(256)
void rope_kernel(float* __restrict__ qkv) {
  int tok = blockIdx.x;
  int t = tok & (T_ - 1);
  int hh = threadIdx.x >> 5, j = threadIdx.x & 31;
  float inv = __expf((float)j * (-logf(10000.f) / 32.f));
  float ang = (float)t * inv;
  float sn = sinf(ang), cs = cosf(ang);
  float* qp = qkv + (size_t)tok * 3 * E_ + hh * Dh_;
  float* kp = qp + E_;
  float q1 = qp[j], q2 = qp[j + HALF_];
  qp[j] = q1 * cs - q2 * sn;
  qp[j + HALF_] = q2 * cs + q1 * sn;
  float k1 = kp[j], k2 = kp[j + HALF_];
  kp[j] = k1 * cs - k2 * sn;
  kp[j + HALF_] = k2 * cs + k1 * sn;
}

// ---------------- flash attention: block = 64 queries of one (b,h), 4 waves x 16 q ----------------
// K/V tiles staged TRANSPOSED in LDS: Kt[d][j] (pitch 65 -> 2-way bank alias, free).
// Output in the reference's scrambled reshape layout:
//   (b,h,t,d) -> row = b*T + h*128 + t/8, col = (t%8)*64 + d
__global__ __launch_bounds__(256)
void attn_flash_kernel(const float* __restrict__ qkv, float* __restrict__ att) {
  __shared__ float Kt[64][65];
  __shared__ float Vt[64][65];
  int b = blockIdx.y >> 3;
  int hh = blockIdx.y & 7;
  int qt0 = blockIdx.x * 64;
  int tid = threadIdx.x;
  int w = tid >> 6, lane = tid & 63;
  const float* base = qkv + (size_t)b * T_ * 3 * E_;

  // Q into registers: lane d holds q[qi][d]
  float qreg[16];
#pragma unroll
  for (int qi = 0; qi < 16; ++qi) {
    int t = qt0 + w * 16 + qi;
    qreg[qi] = base[(size_t)t * 3 * E_ + hh * Dh_ + lane];
  }

  float o[16], m[16], l[16];
#pragma unroll
  for (int qi = 0; qi < 16; ++qi) { o[qi] = 0.f; m[qi] = -1e30f; l[qi] = 0.f; }

  int d = tid & 63, rg = tid >> 6;
  for (int s0 = 0; s0 < T_; s0 += 64) {
    // stage K,V transposed (coalesced global reads)
    const float* kb = base + (size_t)s0 * 3 * E_ + E_ + hh * Dh_ + d;
#pragma unroll
    for (int i = 0; i < 16; ++i) {
      int r = rg * 16 + i;
      const float* p = kb + (size_t)r * 3 * E_;
      Kt[d][r] = p[0];
      Vt[d][r] = p[E_];
    }
    __syncthreads();

    // scores: lane j = key s0+j, 16 queries per wave
    float s[16];
#pragma unroll
    for (int qi = 0; qi < 16; ++qi) s[qi] = 0.f;
#pragma unroll 4
    for (int dd = 0; dd < 64; ++dd) {
      float kd = Kt[dd][lane];
#pragma unroll
      for (int qi = 0; qi < 16; ++qi)
        s[qi] = fmaf(__shfl(qreg[qi], dd, 64), kd, s[qi]);
    }

    // online softmax update per query
#pragma unroll
    for (int qi = 0; qi < 16; ++qi) {
      float sc = s[qi] * 0.125f;  // 1/sqrt(64)
      float tmax = wave_max(sc);
      float nm = fmaxf(m[qi], tmax);
      float alpha = __expf(m[qi] - nm);
      float p = __expf(sc - nm);
      l[qi] = l[qi] * alpha + wave_sum(p);
      o[qi] *= alpha;
      m[qi] = nm;
      s[qi] = p;  // reuse as probability
    }

    // PV: lane = output dim d; p broadcast via shuffle
#pragma unroll 4
    for (int j = 0; j < 64; ++j) {
      float vj = Vt[lane][j];
#pragma unroll
      for (int qi = 0; qi < 16; ++qi)
        o[qi] = fmaf(__shfl(s[qi], j, 64), vj, o[qi]);
    }
    __syncthreads();
  }

#pragma unroll
  for (int qi = 0; qi < 16; ++qi) {
    int t = qt0 + w * 16 + qi;
    size_t row = (size_t)b * T_ + hh * 128 + (t >> 3);
    att[row * E_ + ((t & 7) * Dh_) + lane] = o[qi] / l[qi];
  }
}

// ---------------- router: logits, noisy top-2, gates ----------------
__global__ __launch_bounds__(64)
void router_kernel(const float* __restrict__ h,
                   const float* __restrict__ rw, const float* __restrict__ rb,
                   const float* __restrict__ nw, const float* __restrict__ nb,
                   const float* __restrict__ noise,
                   int* __restrict__ topi, float* __restrict__ topg) {
  int tok = blockIdx.x;
  int lane = threadIdx.x;
  const float* hr = h + (size_t)tok * E_;
  __shared__ float lg[X_], nl[X_];
  for (int xj = 0; xj < X_; ++xj) {
    float a = 0.f, c = 0.f;
    for (int dd = lane; dd < E_; dd += 64) {
      float hv = hr[dd];
      a += hv * rw[xj * E_ + dd];
      c += hv * nw[xj * E_ + dd];
    }
    a = wave_sum(a);
    c = wave_sum(c);
    if (lane == 0) { lg[xj] = a + rb[xj]; nl[xj] = c + nb[xj]; }
  }
  __syncthreads();
  if (lane == 0) {
    float noisy[X_];
#pragma unroll
    for (int xj = 0; xj < X_; ++xj) {
      float nv = nl[xj];
      float sp = fmaxf(nv, 0.f) + log1pf(expf(-fabsf(nv)));
      noisy[xj] = lg[xj] + noise[(size_t)tok * X_ + xj] * sp;
    }
    int i0 = 0;
#pragma unroll
    for (int xj = 1; xj < X_; ++xj) if (noisy[xj] > noisy[i0]) i0 = xj;
    int i1 = -1;
#pragma unroll
    for (int xj = 0; xj < X_; ++xj) {
      if (xj == i0) continue;
      if (i1 < 0 || noisy[xj] > noisy[i1]) i1 = xj;
    }
    float e = __expf(noisy[i1] - noisy[i0]);
    float p0 = 1.f / (1.f + e);
    topi[tok * 2] = i0;
    topi[tok * 2 + 1] = i1;
    topg[tok * 2] = p0;
    topg[tok * 2 + 1] = e * p0;
  }
}

// ---------------- per-expert ordered compaction with capacity ----------------
__global__ __launch_bounds__(256)
void build_lists_kernel(const int* __restrict__ topi, const float* __restrict__ topg,
                        int* __restrict__ elist, float* __restrict__ eg) {
  int ex = blockIdx.x;
  int tid = threadIdx.x;
  constexpr int PER = NTOK / 256;
  int base = tid * PER;
  int cnt = 0;
  for (int i = 0; i < PER; ++i) {
    int t = base + i;
    if (topi[2 * t] == ex || topi[2 * t + 1] == ex) cnt++;
  }
  __shared__ int s[256];
  s[tid] = cnt;
  __syncthreads();
  for (int off = 1; off < 256; off <<= 1) {
    int v = (tid >= off) ? s[tid - off] : 0;
    __syncthreads();
    s[tid] += v;
    __syncthreads();
  }
  int rank = s[tid] - cnt;
  int total = s[255];
  for (int i = 0; i < PER; ++i) {
    int t = base + i;
    int k0 = topi[2 * t], k1 = topi[2 * t + 1];
    if (k0 == ex || k1 == ex) {
      if (rank < CAP_) {
        elist[ex * CAP_ + rank] = t;
        eg[ex * CAP_ + rank] = (k0 == ex) ? topg[2 * t] : topg[2 * t + 1];
      }
      rank++;
    }
  }
  for (int i = total + tid; i < CAP_; i += 256) {
    elist[ex * CAP_ + i] = 0;
    eg[ex * CAP_ + i] = 0.f;
  }
}

// ---------------- pooling + head ----------------
__global__ __launch_bounds__(64)
void pool_score_kernel(const float* __restrict__ h, const float* __restrict__ q,
                       float* __restrict__ s) {
  int tok = blockIdx.x;
  int lane = threadIdx.x;
  const float* hr = h + (size_t)tok * E_;
  float a = 0.f;
  for (int dd = lane; dd < E_; dd += 64) a += hr[dd] * q[dd];
  a = wave_sum(a);
  if (lane == 0) s[tok] = a * (1.f / sqrtf((float)E_));
}

__global__ __launch_bounds__(256)
void pool_softmax_kernel(const float* __restrict__ s, float* __restrict__ w) {
  int b = blockIdx.x, tid = threadIdx.x;
  const float* sr = s + (size_t)b * T_;
  float v[4];
  float mx = -1e30f;
#pragma unroll
  for (int i = 0; i < 4; ++i) { v[i] = sr[tid + 256 * i]; mx = fmaxf(mx, v[i]); }
  __shared__ float red[4];
  mx = wave_max(mx);
  if ((tid & 63) == 0) red[tid >> 6] = mx;
  __syncthreads();
  mx = fmaxf(fmaxf(red[0], red[1]), fmaxf(red[2], red[3]));
  float e[4], sum = 0.f;
#pragma unroll
  for (int i = 0; i < 4; ++i) { e[i] = __expf(v[i] - mx); sum += e[i]; }
  sum = wave_sum(sum);
  __syncthreads();
  if ((tid & 63) == 0) red[tid >> 6] = sum;
  __syncthreads();
  float inv = 1.f / (red[0] + red[1] + red[2] + red[3]);
#pragma unroll
  for (int i = 0; i < 4; ++i) w[(size_t)b * T_ + tid + 256 * i] = e[i] * inv;
}

__global__ __launch_bounds__(512)
void pool_weighted_kernel(const float* __restrict__ w, const float* __restrict__ h,
                          float* __restrict__ pooled) {
  int b = blockIdx.x, e = threadIdx.x;
  float acc = 0.f;
  for (int t = 0; t < T_; ++t) acc += w[(size_t)b * T_ + t] * h[((size_t)b * T_ + t) * E_ + e];
  pooled[(size_t)b * E_ + e] = acc;
}

__global__ __launch_bounds__(256)
void head2_kernel(const float* __restrict__ h1, const float* __restrict__ w2,
                  const float* __restrict__ b2, float* __restrict__ out) {
  int b = blockIdx.x, tid = threadIdx.x;
  float a = 0.f;
  for (int j = tid; j < HID_; j += 256) a += h1[(size_t)b * HID_ + j] * w2[j];
  a = wave_sum(a);
  __shared__ float red[4];
  if ((tid & 63) == 0) red[tid >> 6] = a;
  __syncthreads();
  if (tid == 0) out[b] = red[0] + red[1] + red[2] + red[3] + b2[0];
}

// ---------------- host launcher ----------------
extern "C" void kernel_launch(void* const* d_in, const int* in_sizes, int n_in,
                              void* d_out, int out_size, void* d_ws, size_t ws_size,
                              hipStream_t stream) {
  const float* tok_emb = (const float*)d_in[0];
  const float* pos_emb = (const float*)d_in[1];
  const float* ln1_w = (const float*)d_in[2];
  const float* ln1_b = (const float*)d_in[3];
  const float* ln2_w = (const float*)d_in[4];
  const float* ln2_b = (const float*)d_in[5];
  const float* qkv_w = (const float*)d_in[6];
  const float* out_w = (const float*)d_in[7];
  const float* route_w = (const float*)d_in[8];
  const float* route_b = (const float*)d_in[9];
  const float* noise_w = (const float*)d_in[10];
  const float* noise_b = (const float*)d_in[11];
  const float* exp_w1 = (const float*)d_in[12];
  const float* exp_b1 = (const float*)d_in[13];
  const float* exp_w2 = (const float*)d_in[14];
  const float* exp_b2 = (const float*)d_in[15];
  const float* lnf_w = (const float*)d_in[16];
  const float* lnf_b = (const float*)d_in[17];
  const float* pool_q = (const float*)d_in[18];
  const float* pool_w = (const float*)d_in[19];
  const float* pool_b = (const float*)d_in[20];
  const float* head_w1 = (const float*)d_in[21];
  const float* head_b1 = (const float*)d_in[22];
  const float* head_w2 = (const float*)d_in[23];
  const float* head_b2 = (const float*)d_in[24];
  const int* ids = (const int*)d_in[25];
  const float* rnoise = (const float*)d_in[26];
  float* out = (float*)d_out;
  (void)in_sizes; (void)n_in; (void)out_size;

  // ---- workspace layout (fixed part first, variable-size hid last) ----
  float* ws = (float*)d_ws;
  float* x = ws;        ws += (size_t)NTOK * E_;
  float* h = ws;        ws += (size_t)NTOK * E_;
  float* qkv = ws;      ws += (size_t)NTOK * 3 * E_;
  float* att = ws;      ws += (size_t)NTOK * E_;
  float* sbuf = ws;     ws += NTOK;
  float* wbuf = ws;     ws += NTOK;
  float* pooled = ws;   ws += B_ * E_;
  float* hv = ws;       ws += B_ * HIGH_;
  float* h1 = ws;       ws += B_ * HID_;
  float* topg = ws;     ws += NTOK * 2;
  float* eg = ws;       ws += X_ * CAP_;
  int* topi = (int*)ws; ws += NTOK * 2;
  int* elist = (int*)ws; ws += X_ * CAP_;
  float* hid = (float*)ws;

  size_t used_floats = (size_t)(ws - (float*)d_ws);
  size_t avail = ws_size / 4 > used_floats ? ws_size / 4 - used_floats : 0;
  constexpr size_t HID_FLOATS = (size_t)CAP_ * FF_;  // 4M floats per expert
  int NB = (int)(avail / HID_FLOATS);
  if (NB < 1) NB = 1;
  if (NB > X_) NB = X_;

  embed_kernel<<<NTOK, 256, 0, stream>>>(tok_emb, pos_emb, ids, x);

  for (int l = 0; l < L_; ++l) {
    ln_kernel<<<NTOK, 256, 0, stream>>>(x, ln1_w + l * E_, ln1_b + l * E_, h);
    {
      dim3 g(3 * E_ / BN, NTOK / BM);
      gemm_kernel<<<g, 256, 0, stream>>>(h, E_, qkv_w + (size_t)l * 3 * E_ * E_, nullptr,
                                         qkv, NTOK, 3 * E_, E_, 0, 0);
    }
    rope_kernel<<<NTOK, 256, 0, stream>>>(qkv);
    {
      dim3 g(T_ / 64, B_ * Hn_);
      attn_flash_kernel<<<g, 256, 0, stream>>>(qkv, att);
    }
    {
      dim3 g(E_ / BN, NTOK / BM);  // x += att @ out_w^T
      gemm_kernel<<<g, 256, 0, stream>>>(att, E_, out_w + (size_t)l * E_ * E_, nullptr,
                                         x, NTOK, E_, E_, 0, 1);
    }
    ln_kernel<<<NTOK, 256, 0, stream>>>(x, ln2_w + l * E_, ln2_b + l * E_, h);
    router_kernel<<<NTOK, 64, 0, stream>>>(h, route_w + (size_t)l * X_ * E_, route_b + l * X_,
                                           noise_w + (size_t)l * X_ * E_, noise_b + l * X_,
                                           rnoise + (size_t)l * NTOK * X_, topi, topg);
    build_lists_kernel<<<X_, 256, 0, stream>>>(topi, topg, elist, eg);

    const float* w1 = exp_w1 + (size_t)l * X_ * FF_ * E_;
    const float* b1 = exp_b1 + (size_t)l * X_ * FF_;
    const float* w2 = exp_w2 + (size_t)l * X_ * E_ * FF_;
    const float* b2 = exp_b2 + (size_t)l * X_ * E_;
    for (int e0 = 0; e0 < X_; e0 += NB) {
      int nb = (X_ - e0 < NB) ? (X_ - e0) : NB;
      {
        dim3 g(FF_ / BN, CAP_ / BM, nb);
        gemm_gather_kernel<<<g, 256, 0, stream>>>(h, elist, w1, b1, hid, e0);
      }
      {
        dim3 g(E_ / BN, CAP_ / BM, nb);
        gemm_scatter_kernel<<<g, 256, 0, stream>>>(hid, w2, b2, elist, eg, x, e0);
      }
    }
  }

  ln_kernel<<<NTOK, 256, 0, stream>>>(x, lnf_w, lnf_b, h);
  pool_score_kernel<<<NTOK, 64, 0, stream>>>(h, pool_q, sbuf);
  pool_softmax_kernel<<<B_, 256, 0, stream>>>(sbuf, wbuf);
  pool_weighted_kernel<<<B_, 512, 0, stream>>>(wbuf, h, pooled);
  {
    dim3 g(HIGH_ / BN, 1);
    gemm_kernel<<<g, 256, 0, stream>>>(pooled, E_, pool_w, pool_b, hv, B_, HIGH_, E_, 0, 0);
  }
  {
    dim3 g(HID_ / BN, 1);
    gemm_kernel<<<g, 256, 0, stream>>>(hv, HIGH_, head_w1, head_b1, h1, B_, HIGH_ == 0 ? 0 : HID_, HIGH_, 1, 0);
  }
  head2_kernel<<<B_, 256, 0, stream>>>(h1, head_w2, head_b2, out);
}

// Round 3
// 9567.951 us; speedup vs baseline: 2.9731x; 1.8201x over previous
//
#include <hip/hip_runtime.h>
#include <math.h>

// ---------------- problem constants ----------------
constexpr int L_ = 4, E_ = 512, Hn_ = 8, X_ = 8, Kk_ = 2, V_ = 32000;
constexpr int B_ = 8, T_ = 1024, HIGH_ = 32000, HID_ = 1024;
constexpr int Dh_ = E_ / Hn_;      // 64
constexpr int HALF_ = Dh_ / 2;     // 32
constexpr int NTOK = B_ * T_;      // 8192
constexpr int CAP_ = NTOK * Kk_ / X_; // 2048
constexpr int FF_ = 4 * E_;        // 2048

typedef short short8 __attribute__((ext_vector_type(8)));
typedef float f32x4 __attribute__((ext_vector_type(4)));

__device__ __forceinline__ float wave_sum(float v) {
#pragma unroll
  for (int off = 32; off; off >>= 1) v += __shfl_xor(v, off, 64);
  return v;
}
__device__ __forceinline__ float wave_max(float v) {
#pragma unroll
  for (int off = 32; off; off >>= 1) v = fmaxf(v, __shfl_xor(v, off, 64));
  return v;
}

__device__ __forceinline__ unsigned short f2bf(float x) {
  union { float f; unsigned u; } v; v.f = x;
  unsigned r = v.u + 0x7FFFu + ((v.u >> 16) & 1u);   // RNE
  return (unsigned short)(r >> 16);
}
__device__ __forceinline__ float bf2f(unsigned short h) {
  union { unsigned u; float f; } v; v.u = ((unsigned)h) << 16;
  return v.f;
}

// ---------------- split cast: fp32 -> (hi bf16, lo bf16) planes ----------------
__global__ __launch_bounds__(256)
void split_cast_kernel(const float* __restrict__ src, unsigned short* __restrict__ hi,
                       unsigned short* __restrict__ lo, int n) {
  int i = (blockIdx.x * 256 + threadIdx.x) * 4;
  if (i >= n) return;
  float4 v = *(const float4*)(src + i);
  float vv[4] = {v.x, v.y, v.z, v.w};
#pragma unroll
  for (int j = 0; j < 4; ++j) {
    unsigned short h = f2bf(vv[j]);
    hi[i + j] = h;
    lo[i + j] = f2bf(vv[j] - bf2f(h));
  }
}

// ---------------- embedding ----------------
__global__ __launch_bounds__(256)
void embed_kernel(const float* __restrict__ tok_emb, const float* __restrict__ pos_emb,
                  const int* __restrict__ ids, float* __restrict__ x) {
  int tok = blockIdx.x;
  int t = tok & (T_ - 1);
  int id = ids[tok];
  const float* te = tok_emb + (size_t)id * E_;
  const float* pe = pos_emb + (size_t)t * E_;
  float* xr = x + (size_t)tok * E_;
  int tid = threadIdx.x;
  xr[tid]       = te[tid]       + pe[tid];
  xr[tid + 256] = te[tid + 256] + pe[tid + 256];
}

// ---------------- layernorm ----------------
__global__ __launch_bounds__(256)
void ln_kernel(const float* __restrict__ x, const float* __restrict__ w,
               const float* __restrict__ b, float* __restrict__ o) {
  int row = blockIdx.x, tid = threadIdx.x;
  const float* xr = x + (size_t)row * E_;
  float a0 = xr[tid], a1 = xr[tid + 256];
  __shared__ float red[4];
  float s = wave_sum(a0 + a1);
  if ((tid & 63) == 0) red[tid >> 6] = s;
  __syncthreads();
  float mean = (red[0] + red[1] + red[2] + red[3]) * (1.f / E_);
  float d0 = a0 - mean, d1 = a1 - mean;
  __syncthreads();
  float sq = wave_sum(d0 * d0 + d1 * d1);
  if ((tid & 63) == 0) red[tid >> 6] = sq;
  __syncthreads();
  float var = (red[0] + red[1] + red[2] + red[3]) * (1.f / E_);
  float rstd = 1.f / sqrtf(var + 1e-5f);
  float* orow = o + (size_t)row * E_;
  orow[tid]       = d0 * rstd * w[tid]       + b[tid];
  orow[tid + 256] = d1 * rstd * w[tid + 256] + b[tid + 256];
}

// ======================= split-bf16 MFMA GEMM =======================
// C[M][N] = A[M][K] @ W[N][K]^T  with A,W given as hi/lo bf16 planes.
// acc += aH*bH + aH*bL + aL*bH  (~fp32 precision, 3x MFMA).
// Block 256 = 4 waves (2x2), tile 128x128, BK=32.
// MODE 0: C = acc (plain store)            [qkv]
// MODE 1: C += acc (accumulate)            [att-out residual]
// MODE 2: gather A rows via elist; out = relu(acc+bias) split-stored to Oh/Ol [expert up]
// MODE 3: scatter: x[rows[m]] += (acc+bias[n])*gate[m] atomically           [expert down]
template <int MODE>
__global__ __launch_bounds__(256)
void mfma_gemm(const unsigned short* __restrict__ Ah, const unsigned short* __restrict__ Al,
               int lda,
               const unsigned short* __restrict__ Wh, const unsigned short* __restrict__ Wl,
               const float* __restrict__ bias, float* __restrict__ C,
               unsigned short* __restrict__ Oh, unsigned short* __restrict__ Ol,
               const int* __restrict__ elist, const float* __restrict__ egates, int e0,
               int M, int N, int K) {
  int z = blockIdx.z;
  const int* rows = nullptr;
  const float* gates = nullptr;
  if (MODE == 2) {
    Wh += (size_t)z * N * K;  Wl += (size_t)z * N * K;
    bias += (size_t)(e0 + z) * N;
    rows = elist + (size_t)(e0 + z) * CAP_;
    Oh += (size_t)z * M * N;  Ol += (size_t)z * M * N;
  }
  if (MODE == 3) {
    Ah += (size_t)z * M * K;  Al += (size_t)z * M * K;
    Wh += (size_t)z * N * K;  Wl += (size_t)z * N * K;
    bias += (size_t)(e0 + z) * N;
    rows = elist + (size_t)(e0 + z) * CAP_;
    gates = egates + (size_t)(e0 + z) * CAP_;
  }

  __shared__ unsigned short Ah_s[128][40];
  __shared__ unsigned short Al_s[128][40];
  __shared__ unsigned short Bh_s[128][40];
  __shared__ unsigned short Bl_s[128][40];

  int tid = threadIdx.x;
  int m0 = blockIdx.y * 128, n0 = blockIdx.x * 128;
  int w = tid >> 6, lane = tid & 63;
  int wm = w >> 1, wn = w & 1;
  int lm = lane & 15, q8 = (lane >> 4) * 8, q4 = (lane >> 4) * 4;

  // staging assignment: thread -> (row r, k-half seg)
  int r = tid >> 1, seg = tid & 1;
  size_t arow = (MODE == 2) ? (size_t)rows[m0 + r] : (size_t)(m0 + r);
  const unsigned short* pAh = Ah + arow * (size_t)lda + seg * 16;
  const unsigned short* pAl = Al + arow * (size_t)lda + seg * 16;
  const unsigned short* pWh = Wh + (size_t)(n0 + r) * K + seg * 16;
  const unsigned short* pWl = Wl + (size_t)(n0 + r) * K + seg * 16;

  f32x4 acc[4][4];
#pragma unroll
  for (int i = 0; i < 4; ++i)
#pragma unroll
    for (int j = 0; j < 4; ++j) acc[i][j] = {0.f, 0.f, 0.f, 0.f};

  for (int k0 = 0; k0 < K; k0 += 32) {
    uint4 a0 = *(const uint4*)(pAh + k0);
    uint4 a1 = *(const uint4*)(pAh + k0 + 8);
    uint4 l0 = *(const uint4*)(pAl + k0);
    uint4 l1 = *(const uint4*)(pAl + k0 + 8);
    uint4 b0 = *(const uint4*)(pWh + k0);
    uint4 b1 = *(const uint4*)(pWh + k0 + 8);
    uint4 c0 = *(const uint4*)(pWl + k0);
    uint4 c1 = *(const uint4*)(pWl + k0 + 8);
    *(uint4*)&Ah_s[r][seg * 16]     = a0;
    *(uint4*)&Ah_s[r][seg * 16 + 8] = a1;
    *(uint4*)&Al_s[r][seg * 16]     = l0;
    *(uint4*)&Al_s[r][seg * 16 + 8] = l1;
    *(uint4*)&Bh_s[r][seg * 16]     = b0;
    *(uint4*)&Bh_s[r][seg * 16 + 8] = b1;
    *(uint4*)&Bl_s[r][seg * 16]     = c0;
    *(uint4*)&Bl_s[r][seg * 16 + 8] = c1;
    __syncthreads();

    short8 aH[4], aL[4], bH[4], bL[4];
#pragma unroll
    for (int i = 0; i < 4; ++i) {
      aH[i] = *(const short8*)&Ah_s[wm * 64 + i * 16 + lm][q8];
      aL[i] = *(const short8*)&Al_s[wm * 64 + i * 16 + lm][q8];
    }
#pragma unroll
    for (int j = 0; j < 4; ++j) {
      bH[j] = *(const short8*)&Bh_s[wn * 64 + j * 16 + lm][q8];
      bL[j] = *(const short8*)&Bl_s[wn * 64 + j * 16 + lm][q8];
    }
#pragma unroll
    for (int i = 0; i < 4; ++i)
#pragma unroll
      for (int j = 0; j < 4; ++j) {
        acc[i][j] = __builtin_amdgcn_mfma_f32_16x16x32_bf16(aH[i], bH[j], acc[i][j], 0, 0, 0);
        acc[i][j] = __builtin_amdgcn_mfma_f32_16x16x32_bf16(aH[i], bL[j], acc[i][j], 0, 0, 0);
        acc[i][j] = __builtin_amdgcn_mfma_f32_16x16x32_bf16(aL[i], bH[j], acc[i][j], 0, 0, 0);
      }
    __syncthreads();
  }

  // epilogue: D element (i,j,reg): m = m0+wm*64+i*16+q4+reg, n = n0+wn*64+j*16+lm
#pragma unroll
  for (int i = 0; i < 4; ++i) {
#pragma unroll
    for (int rg = 0; rg < 4; ++rg) {
      int m = m0 + wm * 64 + i * 16 + q4 + rg;
      int tokr = 0; float g = 0.f;
      if (MODE == 3) { tokr = rows[m]; g = gates[m]; }
#pragma unroll
      for (int j = 0; j < 4; ++j) {
        int n = n0 + wn * 64 + j * 16 + lm;
        float v = acc[i][j][rg];
        if (MODE == 0) {
          C[(size_t)m * N + n] = v;
        } else if (MODE == 1) {
          C[(size_t)m * N + n] += v;
        } else if (MODE == 2) {
          v = fmaxf(v + bias[n], 0.f);
          unsigned short hv16 = f2bf(v);
          Oh[(size_t)m * N + n] = hv16;
          Ol[(size_t)m * N + n] = f2bf(v - bf2f(hv16));
        } else {  // MODE 3
          if (g != 0.f)
            atomicAdd(&C[(size_t)tokr * N + n], (v + bias[n]) * g);
        }
      }
    }
  }
}

// ---------------- RoPE in-place on q,k inside qkv ----------------
__global__ __launch_bounds__(256)
void rope_kernel(float* __restrict__ qkv) {
  int tok = blockIdx.x;
  int t = tok & (T_ - 1);
  int hh = threadIdx.x >> 5, j = threadIdx.x & 31;
  float inv = __expf((float)j * (-logf(10000.f) / 32.f));
  float ang = (float)t * inv;
  float sn = sinf(ang), cs = cosf(ang);
  float* qp = qkv + (size_t)tok * 3 * E_ + hh * Dh_;
  float* kp = qp + E_;
  float q1 = qp[j], q2 = qp[j + HALF_];
  qp[j] = q1 * cs - q2 * sn;
  qp[j + HALF_] = q2 * cs + q1 * sn;
  float k1 = kp[j], k2 = kp[j + HALF_];
  kp[j] = k1 * cs - k2 * sn;
  kp[j + HALF_] = k2 * cs + k1 * sn;
}

// ---------------- flash attention (unchanged from round 2, verified) ----------------
__global__ __launch_bounds__(256)
void attn_flash_kernel(const float* __restrict__ qkv, float* __restrict__ att) {
  __shared__ float Kt[64][65];
  __shared__ float Vt[64][65];
  int b = blockIdx.y >> 3;
  int hh = blockIdx.y & 7;
  int qt0 = blockIdx.x * 64;
  int tid = threadIdx.x;
  int w = tid >> 6, lane = tid & 63;
  const float* base = qkv + (size_t)b * T_ * 3 * E_;

  float qreg[16];
#pragma unroll
  for (int qi = 0; qi < 16; ++qi) {
    int t = qt0 + w * 16 + qi;
    qreg[qi] = base[(size_t)t * 3 * E_ + hh * Dh_ + lane];
  }
  float o[16], m[16], l[16];
#pragma unroll
  for (int qi = 0; qi < 16; ++qi) { o[qi] = 0.f; m[qi] = -1e30f; l[qi] = 0.f; }

  int d = tid & 63, rg = tid >> 6;
  for (int s0 = 0; s0 < T_; s0 += 64) {
    const float* kb = base + (size_t)s0 * 3 * E_ + E_ + hh * Dh_ + d;
#pragma unroll
    for (int i = 0; i < 16; ++i) {
      int rr = rg * 16 + i;
      const float* p = kb + (size_t)rr * 3 * E_;
      Kt[d][rr] = p[0];
      Vt[d][rr] = p[E_];
    }
    __syncthreads();

    float s[16];
#pragma unroll
    for (int qi = 0; qi < 16; ++qi) s[qi] = 0.f;
#pragma unroll 4
    for (int dd = 0; dd < 64; ++dd) {
      float kd = Kt[dd][lane];
#pragma unroll
      for (int qi = 0; qi < 16; ++qi)
        s[qi] = fmaf(__shfl(qreg[qi], dd, 64), kd, s[qi]);
    }
#pragma unroll
    for (int qi = 0; qi < 16; ++qi) {
      float sc = s[qi] * 0.125f;
      float tmax = wave_max(sc);
      float nm = fmaxf(m[qi], tmax);
      float alpha = __expf(m[qi] - nm);
      float p = __expf(sc - nm);
      l[qi] = l[qi] * alpha + wave_sum(p);
      o[qi] *= alpha;
      m[qi] = nm;
      s[qi] = p;
    }
#pragma unroll 4
    for (int j = 0; j < 64; ++j) {
      float vj = Vt[lane][j];
#pragma unroll
      for (int qi = 0; qi < 16; ++qi)
        o[qi] = fmaf(__shfl(s[qi], j, 64), vj, o[qi]);
    }
    __syncthreads();
  }
#pragma unroll
  for (int qi = 0; qi < 16; ++qi) {
    int t = qt0 + w * 16 + qi;
    size_t row = (size_t)b * T_ + hh * 128 + (t >> 3);
    att[row * E_ + ((t & 7) * Dh_) + lane] = o[qi] / l[qi];
  }
}

// ---------------- router ----------------
__global__ __launch_bounds__(64)
void router_kernel(const float* __restrict__ h,
                   const float* __restrict__ rw, const float* __restrict__ rb,
                   const float* __restrict__ nw, const float* __restrict__ nb,
                   const float* __restrict__ noise,
                   int* __restrict__ topi, float* __restrict__ topg) {
  int tok = blockIdx.x;
  int lane = threadIdx.x;
  const float* hr = h + (size_t)tok * E_;
  __shared__ float lg[X_], nl[X_];
  for (int xj = 0; xj < X_; ++xj) {
    float a = 0.f, c = 0.f;
    for (int dd = lane; dd < E_; dd += 64) {
      float hv = hr[dd];
      a += hv * rw[xj * E_ + dd];
      c += hv * nw[xj * E_ + dd];
    }
    a = wave_sum(a);
    c = wave_sum(c);
    if (lane == 0) { lg[xj] = a + rb[xj]; nl[xj] = c + nb[xj]; }
  }
  __syncthreads();
  if (lane == 0) {
    float noisy[X_];
#pragma unroll
    for (int xj = 0; xj < X_; ++xj) {
      float nv = nl[xj];
      float sp = fmaxf(nv, 0.f) + log1pf(expf(-fabsf(nv)));
      noisy[xj] = lg[xj] + noise[(size_t)tok * X_ + xj] * sp;
    }
    int i0 = 0;
#pragma unroll
    for (int xj = 1; xj < X_; ++xj) if (noisy[xj] > noisy[i0]) i0 = xj;
    int i1 = -1;
#pragma unroll
    for (int xj = 0; xj < X_; ++xj) {
      if (xj == i0) continue;
      if (i1 < 0 || noisy[xj] > noisy[i1]) i1 = xj;
    }
    float e = __expf(noisy[i1] - noisy[i0]);
    float p0 = 1.f / (1.f + e);
    topi[tok * 2] = i0;
    topi[tok * 2 + 1] = i1;
    topg[tok * 2] = p0;
    topg[tok * 2 + 1] = e * p0;
  }
}

// ---------------- per-expert ordered compaction ----------------
__global__ __launch_bounds__(256)
void build_lists_kernel(const int* __restrict__ topi, const float* __restrict__ topg,
                        int* __restrict__ elist, float* __restrict__ eg) {
  int ex = blockIdx.x;
  int tid = threadIdx.x;
  constexpr int PER = NTOK / 256;
  int base = tid * PER;
  int cnt = 0;
  for (int i = 0; i < PER; ++i) {
    int t = base + i;
    if (topi[2 * t] == ex || topi[2 * t + 1] == ex) cnt++;
  }
  __shared__ int s[256];
  s[tid] = cnt;
  __syncthreads();
  for (int off = 1; off < 256; off <<= 1) {
    int v = (tid >= off) ? s[tid - off] : 0;
    __syncthreads();
    s[tid] += v;
    __syncthreads();
  }
  int rank = s[tid] - cnt;
  int total = s[255];
  for (int i = 0; i < PER; ++i) {
    int t = base + i;
    int k0 = topi[2 * t], k1 = topi[2 * t + 1];
    if (k0 == ex || k1 == ex) {
      if (rank < CAP_) {
        elist[ex * CAP_ + rank] = t;
        eg[ex * CAP_ + rank] = (k0 == ex) ? topg[2 * t] : topg[2 * t + 1];
      }
      rank++;
    }
  }
  for (int i = total + tid; i < CAP_; i += 256) {
    elist[ex * CAP_ + i] = 0;
    eg[ex * CAP_ + i] = 0.f;
  }
}

// ---------------- pooling ----------------
__global__ __launch_bounds__(64)
void pool_score_kernel(const float* __restrict__ h, const float* __restrict__ q,
                       float* __restrict__ s) {
  int tok = blockIdx.x;
  int lane = threadIdx.x;
  const float* hr = h + (size_t)tok * E_;
  float a = 0.f;
  for (int dd = lane; dd < E_; dd += 64) a += hr[dd] * q[dd];
  a = wave_sum(a);
  if (lane == 0) s[tok] = a * (1.f / sqrtf((float)E_));
}

__global__ __launch_bounds__(256)
void pool_softmax_kernel(const float* __restrict__ s, float* __restrict__ w) {
  int b = blockIdx.x, tid = threadIdx.x;
  const float* sr = s + (size_t)b * T_;
  float v[4];
  float mx = -1e30f;
#pragma unroll
  for (int i = 0; i < 4; ++i) { v[i] = sr[tid + 256 * i]; mx = fmaxf(mx, v[i]); }
  __shared__ float red[4];
  mx = wave_max(mx);
  if ((tid & 63) == 0) red[tid >> 6] = mx;
  __syncthreads();
  mx = fmaxf(fmaxf(red[0], red[1]), fmaxf(red[2], red[3]));
  float e[4], sum = 0.f;
#pragma unroll
  for (int i = 0; i < 4; ++i) { e[i] = __expf(v[i] - mx); sum += e[i]; }
  sum = wave_sum(sum);
  __syncthreads();
  if ((tid & 63) == 0) red[tid >> 6] = sum;
  __syncthreads();
  float inv = 1.f / (red[0] + red[1] + red[2] + red[3]);
#pragma unroll
  for (int i = 0; i < 4; ++i) w[(size_t)b * T_ + tid + 256 * i] = e[i] * inv;
}

__global__ __launch_bounds__(512)
void pool_weighted_kernel(const float* __restrict__ w, const float* __restrict__ h,
                          float* __restrict__ pooled) {
  int b = blockIdx.x, e = threadIdx.x;
  float acc = 0.f;
  for (int t = 0; t < T_; ++t) acc += w[(size_t)b * T_ + t] * h[((size_t)b * T_ + t) * E_ + e];
  pooled[(size_t)b * E_ + e] = acc;
}

// ---------------- skinny GEMM #1 (direct): C[8][N] = A[8][512] @ W[N][512]^T + bias ----------------
// grid.x = N/4, block 256 (4 waves, 1 n per wave). A staged in LDS.
__global__ __launch_bounds__(256)
void skinny_direct_kernel(const float* __restrict__ A, const float* __restrict__ W,
                          const float* __restrict__ bias, float* __restrict__ C, int N) {
  __shared__ float As[8 * 512];
  int tid = threadIdx.x;
  for (int i = tid; i < 8 * 512; i += 256) As[i] = A[i];
  __syncthreads();
  int wid = tid >> 6, lane = tid & 63;
  int n = blockIdx.x * 4 + wid;
  float acc[8] = {};
  const float* Wr = W + (size_t)n * 512;
#pragma unroll
  for (int it = 0; it < 2; ++it) {
    int k = it * 256 + lane * 4;
    float4 wv = *(const float4*)(Wr + k);
#pragma unroll
    for (int b = 0; b < 8; ++b) {
      float4 av = *(const float4*)(As + b * 512 + k);
      acc[b] += av.x * wv.x + av.y * wv.y + av.z * wv.z + av.w * wv.w;
    }
  }
#pragma unroll
  for (int b = 0; b < 8; ++b) {
    float s = wave_sum(acc[b]);
    if (lane == 0) C[(size_t)b * N + n] = s + bias[n];
  }
}

// ---------------- h1 init: h1[b][n] = head_b1[n] ----------------
__global__ __launch_bounds__(256)
void init_h1_kernel(const float* __restrict__ b1, float* __restrict__ h1) {
  int idx = blockIdx.x * 256 + threadIdx.x;
  if (idx < 8 * HID_) h1[idx] = b1[idx & (HID_ - 1)];
}

// ---------------- skinny GEMM #2 (K-split atomic): h1[8][1024] += hv[8][32000] @ W[1024][32000]^T ----------------
// grid (256, 25): 4 n per block (one per wave), k-chunk 1280.
__global__ __launch_bounds__(256)
void skinny_split_kernel(const float* __restrict__ A, const float* __restrict__ W,
                         float* __restrict__ C) {
  int tid = threadIdx.x;
  int wid = tid >> 6, lane = tid & 63;
  int n = blockIdx.x * 4 + wid;
  int kbase = blockIdx.y * 1280;
  const float* Wr = W + (size_t)n * HIGH_ + kbase;
  float acc[8] = {};
#pragma unroll
  for (int it = 0; it < 5; ++it) {
    int k = it * 256 + lane * 4;
    float4 wv = *(const float4*)(Wr + k);
#pragma unroll
    for (int b = 0; b < 8; ++b) {
      float4 av = *(const float4*)(A + (size_t)b * HIGH_ + kbase + k);
      acc[b] += av.x * wv.x + av.y * wv.y + av.z * wv.z + av.w * wv.w;
    }
  }
#pragma unroll
  for (int b = 0; b < 8; ++b) {
    float s = wave_sum(acc[b]);
    if (lane == 0) atomicAdd(&C[(size_t)b * HID_ + n], s);
  }
}

// ---------------- head2 with fused relu ----------------
__global__ __launch_bounds__(256)
void head2_kernel(const float* __restrict__ h1, const float* __restrict__ w2,
                  const float* __restrict__ b2, float* __restrict__ out) {
  int b = blockIdx.x, tid = threadIdx.x;
  float a = 0.f;
  for (int j = tid; j < HID_; j += 256) a += fmaxf(h1[(size_t)b * HID_ + j], 0.f) * w2[j];
  a = wave_sum(a);
  __shared__ float red[4];
  if ((tid & 63) == 0) red[tid >> 6] = a;
  __syncthreads();
  if (tid == 0) out[b] = red[0] + red[1] + red[2] + red[3] + b2[0];
}

// ---------------- host launcher ----------------
extern "C" void kernel_launch(void* const* d_in, const int* in_sizes, int n_in,
                              void* d_out, int out_size, void* d_ws, size_t ws_size,
                              hipStream_t stream) {
  const float* tok_emb = (const float*)d_in[0];
  const float* pos_emb = (const float*)d_in[1];
  const float* ln1_w = (const float*)d_in[2];
  const float* ln1_b = (const float*)d_in[3];
  const float* ln2_w = (const float*)d_in[4];
  const float* ln2_b = (const float*)d_in[5];
  const float* qkv_w = (const float*)d_in[6];
  const float* out_w = (const float*)d_in[7];
  const float* route_w = (const float*)d_in[8];
  const float* route_b = (const float*)d_in[9];
  const float* noise_w = (const float*)d_in[10];
  const float* noise_b = (const float*)d_in[11];
  const float* exp_w1 = (const float*)d_in[12];
  const float* exp_b1 = (const float*)d_in[13];
  const float* exp_w2 = (const float*)d_in[14];
  const float* exp_b2 = (const float*)d_in[15];
  const float* lnf_w = (const float*)d_in[16];
  const float* lnf_b = (const float*)d_in[17];
  const float* pool_q = (const float*)d_in[18];
  const float* pool_w = (const float*)d_in[19];
  const float* pool_b = (const float*)d_in[20];
  const float* head_w1 = (const float*)d_in[21];
  const float* head_b1 = (const float*)d_in[22];
  const float* head_w2 = (const float*)d_in[23];
  const float* head_b2 = (const float*)d_in[24];
  const int* ids = (const int*)d_in[25];
  const float* rnoise = (const float*)d_in[26];
  float* out = (float*)d_out;
  (void)in_sizes; (void)n_in; (void)out_size;

  constexpr size_t XE = (size_t)NTOK * E_;          // 4.19M
  constexpr size_t W1EL = (size_t)FF_ * E_;         // 1.05M
  constexpr size_t W2EL = (size_t)E_ * FF_;         // 1.05M
  constexpr size_t HIDEL = (size_t)CAP_ * FF_;      // 4.19M

  char* base = (char*)d_ws;
  size_t cur = 0;
  auto alloc_f = [&](size_t nel) { float* p = (float*)(base + cur); cur += nel * 4; return p; };
  auto alloc_u = [&](size_t nel) { unsigned short* p = (unsigned short*)(base + cur); cur += nel * 2; return p; };

  float* x = alloc_f(XE);
  float* h = alloc_f(XE);           // also holds att
  float* qkv = alloc_f((size_t)NTOK * 3 * E_);
  float* sbuf = alloc_f(NTOK);
  float* wbuf = alloc_f(NTOK);
  float* pooled = alloc_f(B_ * E_);
  float* hv = alloc_f((size_t)B_ * HIGH_);
  float* h1 = alloc_f(B_ * HID_);
  float* topg = alloc_f(NTOK * 2);
  float* eg = alloc_f(X_ * CAP_);
  int* topi = (int*)alloc_f(NTOK * 2);
  int* elist = (int*)alloc_f(X_ * CAP_);
  unsigned short* h2h = alloc_u(XE);   // also att2 hi
  unsigned short* h2l = alloc_u(XE);   // also att2 lo
  unsigned short* qwh = alloc_u((size_t)3 * E_ * E_);
  unsigned short* qwl = alloc_u((size_t)3 * E_ * E_);
  unsigned short* owh = alloc_u((size_t)E_ * E_);
  unsigned short* owl = alloc_u((size_t)E_ * E_);

  // expert-phase buffers: prefer tail of ws; else overlay the (dead) qkv region
  size_t perexp_bytes = 2ull * 2ull * (W1EL + W2EL + HIDEL);  // hi+lo, 2B each
  size_t tail_avail = (ws_size > cur) ? (ws_size - cur) : 0;
  int NB = (int)(tail_avail / perexp_bytes);
  unsigned short* earea;
  if (NB >= 1) {
    earea = (unsigned short*)(base + cur);
    if (NB > X_) NB = X_;
  } else {
    NB = 1;
    earea = (unsigned short*)qkv;  // 50.3 MB region >= 25.2 MB needed
  }
  unsigned short* w1h = earea;
  unsigned short* w1l = w1h + (size_t)NB * W1EL;
  unsigned short* w2h = w1l + (size_t)NB * W1EL;
  unsigned short* w2l = w2h + (size_t)NB * W2EL;
  unsigned short* hidh = w2l + (size_t)NB * W2EL;
  unsigned short* hidl = hidh + (size_t)NB * HIDEL;

  auto cast_grid = [](size_t n) { return dim3((unsigned)((n / 4 + 255) / 256)); };

  embed_kernel<<<NTOK, 256, 0, stream>>>(tok_emb, pos_emb, ids, x);

  for (int l = 0; l < L_; ++l) {
    ln_kernel<<<NTOK, 256, 0, stream>>>(x, ln1_w + l * E_, ln1_b + l * E_, h);
    split_cast_kernel<<<cast_grid(XE), 256, 0, stream>>>(h, h2h, h2l, (int)XE);
    split_cast_kernel<<<cast_grid(3 * E_ * E_), 256, 0, stream>>>(
        qkv_w + (size_t)l * 3 * E_ * E_, qwh, qwl, 3 * E_ * E_);
    mfma_gemm<0><<<dim3(12, 64), 256, 0, stream>>>(h2h, h2l, E_, qwh, qwl, nullptr, qkv,
                                                   nullptr, nullptr, nullptr, nullptr, 0,
                                                   NTOK, 3 * E_, E_);
    rope_kernel<<<NTOK, 256, 0, stream>>>(qkv);
    {
      dim3 g(T_ / 64, B_ * Hn_);
      attn_flash_kernel<<<g, 256, 0, stream>>>(qkv, h);  // att -> h
    }
    split_cast_kernel<<<cast_grid(XE), 256, 0, stream>>>(h, h2h, h2l, (int)XE);  // att2
    split_cast_kernel<<<cast_grid(E_ * E_), 256, 0, stream>>>(
        out_w + (size_t)l * E_ * E_, owh, owl, E_ * E_);
    mfma_gemm<1><<<dim3(4, 64), 256, 0, stream>>>(h2h, h2l, E_, owh, owl, nullptr, x,
                                                  nullptr, nullptr, nullptr, nullptr, 0,
                                                  NTOK, E_, E_);
    ln_kernel<<<NTOK, 256, 0, stream>>>(x, ln2_w + l * E_, ln2_b + l * E_, h);
    split_cast_kernel<<<cast_grid(XE), 256, 0, stream>>>(h, h2h, h2l, (int)XE);
    router_kernel<<<NTOK, 64, 0, stream>>>(h, route_w + (size_t)l * X_ * E_, route_b + l * X_,
                                           noise_w + (size_t)l * X_ * E_, noise_b + l * X_,
                                           rnoise + (size_t)l * NTOK * X_, topi, topg);
    build_lists_kernel<<<X_, 256, 0, stream>>>(topi, topg, elist, eg);

    for (int e0 = 0; e0 < X_; e0 += NB) {
      int nb = (X_ - e0 < NB) ? (X_ - e0) : NB;
      split_cast_kernel<<<cast_grid((size_t)nb * W1EL), 256, 0, stream>>>(
          exp_w1 + ((size_t)l * X_ + e0) * W1EL, w1h, w1l, (int)(nb * W1EL));
      split_cast_kernel<<<cast_grid((size_t)nb * W2EL), 256, 0, stream>>>(
          exp_w2 + ((size_t)l * X_ + e0) * W2EL, w2h, w2l, (int)(nb * W2EL));
      mfma_gemm<2><<<dim3(FF_ / 128, CAP_ / 128, nb), 256, 0, stream>>>(
          h2h, h2l, E_, w1h, w1l, exp_b1 + (size_t)l * X_ * FF_, nullptr,
          hidh, hidl, elist, nullptr, e0, CAP_, FF_, E_);
      mfma_gemm<3><<<dim3(E_ / 128, CAP_ / 128, nb), 256, 0, stream>>>(
          hidh, hidl, FF_, w2h, w2l, exp_b2 + (size_t)l * X_ * E_, x,
          nullptr, nullptr, elist, eg, e0, CAP_, E_, FF_);
    }
  }

  ln_kernel<<<NTOK, 256, 0, stream>>>(x, lnf_w, lnf_b, h);
  pool_score_kernel<<<NTOK, 64, 0, stream>>>(h, pool_q, sbuf);
  pool_softmax_kernel<<<B_, 256, 0, stream>>>(sbuf, wbuf);
  pool_weighted_kernel<<<B_, 512, 0, stream>>>(wbuf, h, pooled);
  skinny_direct_kernel<<<HIGH_ / 4, 256, 0, stream>>>(pooled, pool_w, pool_b, hv, HIGH_);
  init_h1_kernel<<<(8 * HID_ + 255) / 256, 256, 0, stream>>>(head_b1, h1);
  {
    dim3 g(HID_ / 4, 25);
    skinny_split_kernel<<<g, 256, 0, stream>>>(hv, head_w1, h1);
  }
  head2_kernel<<<B_, 256, 0, stream>>>(h1, head_w2, head_b2, out);
}